// Round 1
// baseline (297.351 us; speedup 1.0000x reference)
//
#include <hip/hip_runtime.h>

// WaveletLayer: B=8192 rows, DEPTH=4096, db2 DWT 3 scales + perm + inverse.
// One workgroup per row; entire pipeline in LDS.
//
// c layout (pre-perm): [a3: 0..514) [d3: 514..1028) [d2: 1028..2054) [d1: 2054..4103)
// recon slices of permuted cp: a=cp[0:514), d3'=cp[2049:2563), d2'=cp[1026:2052), d1'=cp[514:2563)

#define NTHREADS 256

__device__ __forceinline__ float getz(const float* b, int t, int N) {
    return ((unsigned)t < (unsigned)N) ? b[t] : 0.0f;
}

__global__ __launch_bounds__(NTHREADS) void wavelet_fused(
    const float* __restrict__ x,
    const float* __restrict__ diag_b,
    const float* __restrict__ diag_g,
    const float* __restrict__ diag_s,
    const float* __restrict__ dec_lo,
    const float* __restrict__ dec_hi,
    const float* __restrict__ rec_lo,
    const float* __restrict__ rec_hi,
    const int*   __restrict__ perm_idx,
    float* __restrict__ out)
{
    __shared__ __align__(16) float P[4104];  // a0 -> a2 -> cp (permuted coeffs)
    __shared__ __align__(16) float Q[4104];  // c (concat coeffs) -> recon L2 out
    __shared__ __align__(16) float R[2052];  // a1 -> recon L1 out

    const int tid = threadIdx.x;
    const long row = blockIdx.x;

    const float lo0=dec_lo[0], lo1=dec_lo[1], lo2=dec_lo[2], lo3=dec_lo[3];
    const float hi0=dec_hi[0], hi1=dec_hi[1], hi2=dec_hi[2], hi3=dec_hi[3];
    const float rl0=rec_lo[0], rl1=rec_lo[1], rl2=rec_lo[2], rl3=rec_lo[3];
    const float rh0=rec_hi[0], rh1=rec_hi[1], rh2=rec_hi[2], rh3=rec_hi[3];

    // ---- load row, apply diag_b (float4 vectorized) ----
    const float4* xr = (const float4*)(x + row * 4096);
    const float4* bb = (const float4*)diag_b;
    float4* P4 = (float4*)P;
    for (int i = tid; i < 1024; i += NTHREADS) {
        float4 v = xr[i], w = bb[i];
        v.x *= w.x; v.y *= w.y; v.z *= w.z; v.w *= w.w;
        P4[i] = v;
    }
    __syncthreads();

    // ---- forward scale 1: P(4096) -> a1 in R(2049), d1 in Q[2054..4103) ----
    for (int n = tid; n < 2049; n += NTHREADS) {
        float A0 = getz(P, 2*n+1, 4096);
        float A1 = getz(P, 2*n,   4096);
        float A2 = getz(P, 2*n-1, 4096);
        float A3 = getz(P, 2*n-2, 4096);
        R[n]        = lo0*A0 + lo1*A1 + lo2*A2 + lo3*A3;
        Q[2054 + n] = hi0*A0 + hi1*A1 + hi2*A2 + hi3*A3;
    }
    __syncthreads();

    // ---- forward scale 2: R(2049) -> a2 in P[0..1026), d2 in Q[1028..2054) ----
    for (int n = tid; n < 1026; n += NTHREADS) {
        float A0 = getz(R, 2*n+1, 2049);
        float A1 = getz(R, 2*n,   2049);
        float A2 = getz(R, 2*n-1, 2049);
        float A3 = getz(R, 2*n-2, 2049);
        P[n]        = lo0*A0 + lo1*A1 + lo2*A2 + lo3*A3;
        Q[1028 + n] = hi0*A0 + hi1*A1 + hi2*A2 + hi3*A3;
    }
    __syncthreads();

    // ---- forward scale 3: P(1026) -> a3 in Q[0..514), d3 in Q[514..1028) ----
    for (int n = tid; n < 514; n += NTHREADS) {
        float A0 = getz(P, 2*n+1, 1026);
        float A1 = getz(P, 2*n,   1026);
        float A2 = getz(P, 2*n-1, 1026);
        float A3 = getz(P, 2*n-2, 1026);
        Q[n]       = lo0*A0 + lo1*A1 + lo2*A2 + lo3*A3;
        Q[514 + n] = hi0*A0 + hi1*A1 + hi2*A2 + hi3*A3;
    }
    __syncthreads();

    // ---- permute + diag_g: cp[i] = c[perm[i]] * g[i], into P ----
    for (int i = tid; i < 4103; i += NTHREADS) {
        P[i] = Q[perm_idx[i]] * diag_g[i];
    }
    __syncthreads();

    // ---- recon L1: a=P[0:514), d=P[2049:2563) -> R[0:1026) ----
    for (int p = tid; p < 513; p += NTHREADS) {
        float a0 = P[p],        a1 = P[p+1];
        float d0 = P[2049 + p], d1 = P[2049 + p + 1];
        R[2*p]   = rl2*a0 + rl0*a1 + rh2*d0 + rh0*d1;
        R[2*p+1] = rl3*a0 + rl1*a1 + rh3*d0 + rh1*d1;
    }
    __syncthreads();

    // ---- recon L2: a=R(1026), d=P[1026:2052) -> Q[0:2050) ----
    for (int p = tid; p < 1025; p += NTHREADS) {
        float a0 = R[p],        a1 = R[p+1];
        float d0 = P[1026 + p], d1 = P[1026 + p + 1];
        Q[2*p]   = rl2*a0 + rl0*a1 + rh2*d0 + rh0*d1;
        Q[2*p+1] = rl3*a0 + rl1*a1 + rh3*d0 + rh1*d1;
    }
    __syncthreads();

    // ---- recon L3: a=Q[0:2049) (trimmed), d=P[514:2563) -> out * diag_s ----
    const float4* ss = (const float4*)diag_s;
    float4* outr = (float4*)(out + row * 4096);
    for (int q = tid; q < 1024; q += NTHREADS) {
        int h = 2 * q;
        float a0 = Q[h],       a1 = Q[h+1],       a2 = Q[h+2];
        float d0 = P[514 + h], d1 = P[514 + h+1], d2 = P[514 + h+2];
        float4 s4 = ss[q];
        float4 o;
        o.x = (rl2*a0 + rl0*a1 + rh2*d0 + rh0*d1) * s4.x;
        o.y = (rl3*a0 + rl1*a1 + rh3*d0 + rh1*d1) * s4.y;
        o.z = (rl2*a1 + rl0*a2 + rh2*d1 + rh0*d2) * s4.z;
        o.w = (rl3*a1 + rl1*a2 + rh3*d1 + rh1*d2) * s4.w;
        outr[q] = o;
    }
}

extern "C" void kernel_launch(void* const* d_in, const int* in_sizes, int n_in,
                              void* d_out, int out_size, void* d_ws, size_t ws_size,
                              hipStream_t stream) {
    const float* x       = (const float*)d_in[0];
    const float* diag_b  = (const float*)d_in[1];
    const float* diag_g  = (const float*)d_in[2];
    const float* diag_s  = (const float*)d_in[3];
    const float* dec_lo  = (const float*)d_in[4];
    const float* dec_hi  = (const float*)d_in[5];
    const float* rec_lo  = (const float*)d_in[6];
    const float* rec_hi  = (const float*)d_in[7];
    const int*   perm    = (const int*)d_in[8];
    float* out = (float*)d_out;

    const int B = in_sizes[0] / 4096;  // 8192 rows
    wavelet_fused<<<B, NTHREADS, 0, stream>>>(
        x, diag_b, diag_g, diag_s, dec_lo, dec_hi, rec_lo, rec_hi, perm, out);
}

// Round 2
// 261.431 us; speedup vs baseline: 1.1374x; 1.1374x over previous
//
#include <hip/hip_runtime.h>

// WaveletLayer: B=8192 rows, DEPTH=4096, db2 DWT 3 scales + perm + inverse.
// One workgroup (512 thr) per row; entire pipeline in LDS, 2 overlaid buffers.
//
// c layout (pre-perm): [a3: 0..514) [d3: 514..1028) [d2: 1028..2054) [d1: 2054..4103)
// recon slices of permuted cp: a=cp[0:514), d3'=cp[2049:2563), d2'=cp[1026:2052), d1'=cp[514:2563)
//
// Buffer lifetimes (each row = one barrier epoch boundary):
//   A: a0[0:4096)  ->  a2[0:1026)+d2[1026:2052)  ->  cp[0:4103)
//   C: a1[0:2049)+d1[2054:4103) -> full c[0:4103) -> r1[0:1026) -> +r2[1028:3078)
// LDS = 2 x 4104 floats = 32832 B  ->  4 blocks/CU x 8 waves = 32 waves/CU (100%).

#define NT 512

__device__ __forceinline__ float getz(const float* b, int t, int N) {
    return ((unsigned)t < (unsigned)N) ? b[t] : 0.0f;
}

__global__ __launch_bounds__(NT, 8) void wavelet_fused(
    const float* __restrict__ x,
    const float* __restrict__ diag_b,
    const float* __restrict__ diag_g,
    const float* __restrict__ diag_s,
    const float* __restrict__ dec_lo,
    const float* __restrict__ dec_hi,
    const float* __restrict__ rec_lo,
    const float* __restrict__ rec_hi,
    const int*   __restrict__ perm_idx,
    float* __restrict__ out)
{
    __shared__ __align__(16) float A[4104];
    __shared__ __align__(16) float C[4104];

    const int tid = threadIdx.x;
    const long row = blockIdx.x;

    const float lo0=dec_lo[0], lo1=dec_lo[1], lo2=dec_lo[2], lo3=dec_lo[3];
    const float hi0=dec_hi[0], hi1=dec_hi[1], hi2=dec_hi[2], hi3=dec_hi[3];
    const float rl0=rec_lo[0], rl1=rec_lo[1], rl2=rec_lo[2], rl3=rec_lo[3];
    const float rh0=rec_hi[0], rh1=rec_hi[1], rh2=rec_hi[2], rh3=rec_hi[3];

    // ---- load row, apply diag_b -> A (a0) ----
    {
        const float4* xr = (const float4*)(x + row * 4096);
        const float4* bb = (const float4*)diag_b;
        float4* A4 = (float4*)A;
        for (int i = tid; i < 1024; i += NT) {
            float4 v = xr[i], w = bb[i];
            v.x *= w.x; v.y *= w.y; v.z *= w.z; v.w *= w.w;
            A4[i] = v;
        }
    }
    __syncthreads();

    // ---- scale 1: A=a0(4096) -> a1 C[0:2049), d1 C[2054:4103) ----
    for (int n = tid; n < 2049; n += NT) {
        float A0 = getz(A, 2*n+1, 4096);
        float A1 = getz(A, 2*n,   4096);
        float A2 = getz(A, 2*n-1, 4096);
        float A3 = getz(A, 2*n-2, 4096);
        C[n]        = lo0*A0 + lo1*A1 + lo2*A2 + lo3*A3;
        C[2054 + n] = hi0*A0 + hi1*A1 + hi2*A2 + hi3*A3;
    }
    __syncthreads();

    // ---- scale 2: C[0:2049)=a1 -> a2 A[0:1026), d2 A[1026:2052) ----
    for (int n = tid; n < 1026; n += NT) {
        float A0 = getz(C, 2*n+1, 2049);
        float A1 = getz(C, 2*n,   2049);
        float A2 = getz(C, 2*n-1, 2049);
        float A3 = getz(C, 2*n-2, 2049);
        A[n]        = lo0*A0 + lo1*A1 + lo2*A2 + lo3*A3;
        A[1026 + n] = hi0*A0 + hi1*A1 + hi2*A2 + hi3*A3;
    }
    __syncthreads();

    // ---- scale 3: A[0:1026)=a2 -> a3 C[0:514), d3 C[514:1028);
    //      also move d2 into place: C[1028+j] = A[1026+j] ----
    for (int n = tid; n < 514; n += NT) {
        float A0 = getz(A, 2*n+1, 1026);
        float A1 = getz(A, 2*n,   1026);
        float A2 = getz(A, 2*n-1, 1026);
        float A3 = getz(A, 2*n-2, 1026);
        C[n]       = lo0*A0 + lo1*A1 + lo2*A2 + lo3*A3;
        C[514 + n] = hi0*A0 + hi1*A1 + hi2*A2 + hi3*A3;
    }
    for (int j = tid; j < 1026; j += NT) {
        C[1028 + j] = A[1026 + j];
    }
    __syncthreads();

    // ---- permute + diag_g: cp[i] = c[perm[i]] * g[i] -> A ----
    for (int i = tid; i < 4103; i += NT) {
        A[i] = C[perm_idx[i]] * diag_g[i];
    }
    __syncthreads();

    // ---- recon L1: a=A[0:514), d=A[2049:2563) -> r1 = C[0:1026) ----
    {
        float2* C2 = (float2*)C;
        for (int p = tid; p < 513; p += NT) {
            float a0 = A[p],        a1 = A[p+1];
            float d0 = A[2049 + p], d1 = A[2050 + p];
            float2 w;
            w.x = rl2*a0 + rl0*a1 + rh2*d0 + rh0*d1;
            w.y = rl3*a0 + rl1*a1 + rh3*d0 + rh1*d1;
            C2[p] = w;
        }
    }
    __syncthreads();

    // ---- recon L2: a=C[0:1026)=r1, d=A[1026:2052) -> r2 = C[1028:3078) ----
    {
        float2* R2 = (float2*)(C + 1028);
        for (int p = tid; p < 1025; p += NT) {
            float a0 = C[p],        a1 = C[p+1];
            float d0 = A[1026 + p], d1 = A[1027 + p];
            float2 w;
            w.x = rl2*a0 + rl0*a1 + rh2*d0 + rh0*d1;
            w.y = rl3*a0 + rl1*a1 + rh3*d0 + rh1*d1;
            R2[p] = w;
        }
    }
    __syncthreads();

    // ---- recon L3: a=C[1028:3077) (r2 trimmed), d=A[514:2563) -> out*diag_s ----
    {
        const float4* ss = (const float4*)diag_s;
        float4* outr = (float4*)(out + row * 4096);
        for (int q = tid; q < 1024; q += NT) {
            int h = 2 * q;
            float a0 = C[1028 + h], a1 = C[1029 + h], a2 = C[1030 + h];
            float d0 = A[514 + h],  d1 = A[515 + h],  d2 = A[516 + h];
            float4 s4 = ss[q];
            float4 o;
            o.x = (rl2*a0 + rl0*a1 + rh2*d0 + rh0*d1) * s4.x;
            o.y = (rl3*a0 + rl1*a1 + rh3*d0 + rh1*d1) * s4.y;
            o.z = (rl2*a1 + rl0*a2 + rh2*d1 + rh0*d2) * s4.z;
            o.w = (rl3*a1 + rl1*a2 + rh3*d1 + rh1*d2) * s4.w;
            outr[q] = o;
        }
    }
}

extern "C" void kernel_launch(void* const* d_in, const int* in_sizes, int n_in,
                              void* d_out, int out_size, void* d_ws, size_t ws_size,
                              hipStream_t stream) {
    const float* x       = (const float*)d_in[0];
    const float* diag_b  = (const float*)d_in[1];
    const float* diag_g  = (const float*)d_in[2];
    const float* diag_s  = (const float*)d_in[3];
    const float* dec_lo  = (const float*)d_in[4];
    const float* dec_hi  = (const float*)d_in[5];
    const float* rec_lo  = (const float*)d_in[6];
    const float* rec_hi  = (const float*)d_in[7];
    const int*   perm    = (const int*)d_in[8];
    float* out = (float*)d_out;

    const int B = in_sizes[0] / 4096;  // 8192 rows
    wavelet_fused<<<B, NT, 0, stream>>>(
        x, diag_b, diag_g, diag_s, dec_lo, dec_hi, rec_lo, rec_hi, perm, out);
}

// Round 3
// 257.033 us; speedup vs baseline: 1.1569x; 1.0171x over previous
//
#include <hip/hip_runtime.h>

// WaveletLayer: B=8192 rows, DEPTH=4096, db2 DWT 3 scales + perm + inverse.
// One 512-thread workgroup per row. Two LDS buffers, zero-padded so no
// bounds checks are needed; all structured LDS accesses are conflict-free
// (b64/b128 with contiguous lane tiling).
//
// Logical c layout: [a3:0..514 | d3:514..1028 | d2:1028..2054 | d1:2054..4103]
// Physical in C:     a3@0, d3@514, d2@1028 (copied), d1@2060 (gather remaps +6;
//                    gap C[2049..2060) is the zero-pad for a1's edge reads).
// Buffer lifetimes:
//   A: a0[0:4096) -> a2[0:1026)+gap[1026:1032)+d2[1032:2058) -> cp[0:4103)
//   C: a1[0:2049)+gap+d1[2060:4109) -> c -> r1[0:1026) -> +r2[1028:3078)
// LDS = 2 x 4116 floats = 32.9 KB -> 4 blocks/CU x 8 waves = 32 waves/CU.

#define NT 512

__global__ __launch_bounds__(NT, 8) void wavelet_fused(
    const float* __restrict__ x,
    const float* __restrict__ diag_b,
    const float* __restrict__ diag_g,
    const float* __restrict__ diag_s,
    const float* __restrict__ dec_lo,
    const float* __restrict__ dec_hi,
    const float* __restrict__ rec_lo,
    const float* __restrict__ rec_hi,
    const int*   __restrict__ perm_idx,
    float* __restrict__ out)
{
    __shared__ __align__(16) float rawA[4 + 4112];
    __shared__ __align__(16) float rawC[4 + 4112];
    float* const A = rawA + 4;   // 16B-aligned
    float* const C = rawC + 4;   // 16B-aligned

    const int tid = threadIdx.x;
    const long row = blockIdx.x;

    const float lo0=dec_lo[0], lo1=dec_lo[1], lo2=dec_lo[2], lo3=dec_lo[3];
    const float hi0=dec_hi[0], hi1=dec_hi[1], hi2=dec_hi[2], hi3=dec_hi[3];
    const float rl0=rec_lo[0], rl1=rec_lo[1], rl2=rec_lo[2], rl3=rec_lo[3];
    const float rh0=rec_hi[0], rh1=rec_hi[1], rh2=rec_hi[2], rh3=rec_hi[3];

    // ---- stage 0: load row * diag_b -> A; zero all pads ----
    {
        const float4* xr = (const float4*)(x + row * 4096);
        const float4* bb = (const float4*)diag_b;
        float4* A4 = (float4*)A;
        for (int i = tid; i < 1024; i += NT) {
            float4 v = xr[i], w = bb[i];
            v.x *= w.x; v.y *= w.y; v.z *= w.z; v.w *= w.w;
            A4[i] = v;
        }
        if (tid < 4)  rawA[tid] = 0.0f;        // A[-4..0)
        if (tid < 8)  A[4096 + tid] = 0.0f;    // A[4096..4104)
        if (tid < 4)  rawC[tid] = 0.0f;        // C[-4..0)
        if (tid < 11) C[2049 + tid] = 0.0f;    // C[2049..2060) (a1 zero-pad)
    }
    __syncthreads();

    // ---- s1: a0=A(4096) -> a1=C[0:2049), d1=C[2060:4109) ----
    for (int n = tid; n < 2049; n += NT) {
        float2 u0 = *(const float2*)(A + 2*n - 2);  // a[2n-2], a[2n-1]
        float2 u1 = *(const float2*)(A + 2*n);      // a[2n],   a[2n+1]
        C[n]        = lo0*u1.y + lo1*u1.x + lo2*u0.y + lo3*u0.x;
        C[2060 + n] = hi0*u1.y + hi1*u1.x + hi2*u0.y + hi3*u0.x;
    }
    __syncthreads();

    // ---- s2: a1=C[0:2049) -> a2=A[0:1026), d2=A[1032:2058); zero A gap ----
    if (tid < 6) A[1026 + tid] = 0.0f;              // a2 zero-pad for s3
    for (int n = tid; n < 1026; n += NT) {
        float2 u0 = *(const float2*)(C + 2*n - 2);
        float2 u1 = *(const float2*)(C + 2*n);
        A[n]        = lo0*u1.y + lo1*u1.x + lo2*u0.y + lo3*u0.x;
        A[1032 + n] = hi0*u1.y + hi1*u1.x + hi2*u0.y + hi3*u0.x;
    }
    __syncthreads();

    // ---- s3: a2=A[0:1026) -> a3=C[0:514), d3=C[514:1028); copy d2 into c ----
    for (int n = tid; n < 514; n += NT) {
        float2 u0 = *(const float2*)(A + 2*n - 2);
        float2 u1 = *(const float2*)(A + 2*n);
        C[n]       = lo0*u1.y + lo1*u1.x + lo2*u0.y + lo3*u0.x;
        C[514 + n] = hi0*u1.y + hi1*u1.x + hi2*u0.y + hi3*u0.x;
    }
    for (int j = tid; j < 513; j += NT) {
        *(float2*)(C + 1028 + 2*j) = *(const float2*)(A + 1032 + 2*j);
    }
    __syncthreads();

    // ---- gather: cp[i] = c[perm[i]] * g[i] -> A[0:4103) ----
    for (int q = tid; q < 1025; q += NT) {
        int4  pj = ((const int4*)perm_idx)[q];
        float4 g4 = ((const float4*)diag_g)[q];
        float4 v;
        v.x = C[pj.x + (pj.x >= 2054 ? 6 : 0)] * g4.x;
        v.y = C[pj.y + (pj.y >= 2054 ? 6 : 0)] * g4.y;
        v.z = C[pj.z + (pj.z >= 2054 ? 6 : 0)] * g4.z;
        v.w = C[pj.w + (pj.w >= 2054 ? 6 : 0)] * g4.w;
        ((float4*)A)[q] = v;
    }
    if (tid < 3) {
        int i = 4100 + tid;
        int j = perm_idx[i];
        A[i] = C[j + (j >= 2054 ? 6 : 0)] * diag_g[i];
    }
    __syncthreads();

    // ---- r1: a=cp[0:514), d=cp[2049:2563) -> r1 = C[0:1026); 2 pairs/thread ----
    for (int u = tid; u < 257; u += NT) {
        int p0 = 2 * u;
        float a0v = A[p0],        a1v = A[p0 + 1],    a2v = A[p0 + 2];
        float d0v = A[2049 + p0], d1v = A[2050 + p0], d2v = A[2051 + p0];
        float4 w;
        w.x = rl2*a0v + rl0*a1v + rh2*d0v + rh0*d1v;
        w.y = rl3*a0v + rl1*a1v + rh3*d0v + rh1*d1v;
        w.z = rl2*a1v + rl0*a2v + rh2*d1v + rh0*d2v;
        w.w = rl3*a1v + rl1*a2v + rh3*d1v + rh1*d2v;
        if (u < 256) *(float4*)(C + 4*u) = w;
        else         { C[4*u] = w.x; C[4*u + 1] = w.y; }   // pair 512 only
    }
    __syncthreads();

    // ---- r2: a=r1=C[0:1026), d=cp[1026:2052) -> r2 = C[1028:3078) ----
    for (int u = tid; u < 513; u += NT) {
        int p0 = 2 * u;
        float a0v = C[p0], a1v = C[p0 + 1], a2v = C[p0 + 2];
        float2 dd = *(const float2*)(A + 1026 + p0);
        float d2v = A[1028 + p0];
        float4 w;
        w.x = rl2*a0v + rl0*a1v + rh2*dd.x + rh0*dd.y;
        w.y = rl3*a0v + rl1*a1v + rh3*dd.x + rh1*dd.y;
        w.z = rl2*a1v + rl0*a2v + rh2*dd.y + rh0*d2v;
        w.w = rl3*a1v + rl1*a2v + rh3*dd.y + rh1*d2v;
        if (u < 512) *(float4*)(C + 1028 + 4*u) = w;
        else         { C[1028 + 4*u] = w.x; C[1028 + 4*u + 1] = w.y; }
    }
    __syncthreads();

    // ---- r3: a=r2 (trimmed), d=cp[514:2563) -> out * diag_s; 2 quads/thread ----
    {
        const float4* ss = (const float4*)diag_s;
        float4* outr = (float4*)(out + row * 4096);
        for (int u = tid; u < 512; u += NT) {
            int b = 1028 + 4 * u;
            float4 aa = *(const float4*)(C + b);
            float a4v = C[b + 4];
            float2 dd0 = *(const float2*)(A + 514 + 4*u);
            float2 dd1 = *(const float2*)(A + 516 + 4*u);
            float d4v  = A[518 + 4*u];
            float4 s0 = ss[2*u], s1 = ss[2*u + 1];
            float4 o0, o1;
            o0.x = (rl2*aa.x + rl0*aa.y + rh2*dd0.x + rh0*dd0.y) * s0.x;
            o0.y = (rl3*aa.x + rl1*aa.y + rh3*dd0.x + rh1*dd0.y) * s0.y;
            o0.z = (rl2*aa.y + rl0*aa.z + rh2*dd0.y + rh0*dd1.x) * s0.z;
            o0.w = (rl3*aa.y + rl1*aa.z + rh3*dd0.y + rh1*dd1.x) * s0.w;
            o1.x = (rl2*aa.z + rl0*aa.w + rh2*dd1.x + rh0*dd1.y) * s1.x;
            o1.y = (rl3*aa.z + rl1*aa.w + rh3*dd1.x + rh1*dd1.y) * s1.y;
            o1.z = (rl2*aa.w + rl0*a4v  + rh2*dd1.y + rh0*d4v ) * s1.z;
            o1.w = (rl3*aa.w + rl1*a4v  + rh3*dd1.y + rh1*d4v ) * s1.w;
            outr[2*u]     = o0;
            outr[2*u + 1] = o1;
        }
    }
}

extern "C" void kernel_launch(void* const* d_in, const int* in_sizes, int n_in,
                              void* d_out, int out_size, void* d_ws, size_t ws_size,
                              hipStream_t stream) {
    const float* x       = (const float*)d_in[0];
    const float* diag_b  = (const float*)d_in[1];
    const float* diag_g  = (const float*)d_in[2];
    const float* diag_s  = (const float*)d_in[3];
    const float* dec_lo  = (const float*)d_in[4];
    const float* dec_hi  = (const float*)d_in[5];
    const float* rec_lo  = (const float*)d_in[6];
    const float* rec_hi  = (const float*)d_in[7];
    const int*   perm    = (const int*)d_in[8];
    float* out = (float*)d_out;

    const int B = in_sizes[0] / 4096;  // 8192 rows
    wavelet_fused<<<B, NT, 0, stream>>>(
        x, diag_b, diag_g, diag_s, dec_lo, dec_hi, rec_lo, rec_hi, perm, out);
}